// Round 15
// baseline (6500.691 us; speedup 1.0000x reference)
//
#include <hip/hip_runtime.h>
#include <hip/hip_bf16.h>
#include <hip/hip_fp16.h>
#include <math.h>
#include <stdint.h>

// Problem constants
#define I_DIM 64
#define H_DIM 256
#define NC    10
#define S1    500
#define S2    41
#define BATCH 128
#define ST    (S1 + S2)          // 541
#define F1    (ST * H_DIM)       // 138496
#define KTOT  (I_DIM + H_DIM)    // 320
#define NKK   10                 // K-steps of 32
#define MB    16                 // batch rows per chunk
#define VH_STRIDE 328            // fp16 row stride for [x|h] (320 + 8 pad)

// fc1 split-K params
#define KC   512
#define KCH  32
#define NSLICE ((F1 + KC - 1) / KC)   // 271

typedef _Float16 f16x8 __attribute__((ext_vector_type(8)));
typedef _Float16 f16x4 __attribute__((ext_vector_type(4)));
typedef float    f32x4 __attribute__((ext_vector_type(4)));

__device__ __forceinline__ float sigmoidf(float x) {
    return 1.0f / (1.0f + __expf(-x));
}
__device__ __forceinline__ float tanh_fast(float x) {
    float e = __expf(2.0f * x);
    return 1.0f - 2.0f / (e + 1.0f);
}

// LDS-only barrier (r13-proven): all cross-thread data at this sync point is
// LDS (vh), so wait lgkmcnt only — skip __syncthreads' vmcnt(0) drain of the
// in-flight hseq stores / x prefetch (not consumed across the barrier).
// SALU-only asm: compiler vmcnt bookkeeping for its own loads stays valid.
#define BAR_LDS() do {                                                  \
    __builtin_amdgcn_sched_barrier(0);                                  \
    asm volatile("s_waitcnt lgkmcnt(0)\n\ts_barrier" ::: "memory");     \
    __builtin_amdgcn_sched_barrier(0);                                  \
} while (0)

// ---------------------------------------------------------------------------
// Pack [w_ih | w_hh] (fp32) into MFMA B-fragment order, fp16 (same as r6-r14):
//   Bp[ ((l*NKK + kk)*64 + ntg)*64 + lane ]  (one f16x8 per lane)
//   n = ntg*16 + (lane&15);  k = kk*32 + (lane>>4)*8 + e
// A-frags are read from LDS with the SAME (lane,e)->k map, so the contraction
// is correct independent of the HW's internal k-order (bijection invariance).
// ---------------------------------------------------------------------------
__global__ __launch_bounds__(256) void prep_pack_b(
        const float* __restrict__ wih1, const float* __restrict__ whh1,
        const float* __restrict__ wih2, const float* __restrict__ whh2,
        f16x8* __restrict__ Bp) {
    int gid = blockIdx.x * 256 + threadIdx.x;      // 0..81919
    int lane = gid & 63;
    int frag = gid >> 6;                           // 0..1279
    int ntg  = frag & 63;
    int rest = frag >> 6;                          // 0..19
    int kk   = rest % NKK;
    int l    = rest / NKK;
    const float* wih = l ? wih2 : wih1;
    const float* whh = l ? whh2 : whh1;
    int n  = ntg * 16 + (lane & 15);               // gate row 0..1023
    int k0 = kk * 32 + (lane >> 4) * 8;
    f16x8 v;
    #pragma unroll
    for (int e = 0; e < 8; ++e) {
        int k = k0 + e;
        float f = (k < I_DIM) ? wih[(size_t)n * I_DIM + k]
                              : whh[(size_t)n * H_DIM + (k - I_DIM)];
        v[e] = (_Float16)f;
    }
    Bp[gid] = v;
}

__global__ __launch_bounds__(256) void prep_bias(
        const float* __restrict__ bih1, const float* __restrict__ bhh1,
        const float* __restrict__ bih2, const float* __restrict__ bhh2,
        float* __restrict__ bsum) {
    int gid = blockIdx.x * 256 + threadIdx.x;      // 0..2047
    if (gid >= 2048) return;
    int l = gid >> 10, n = gid & 1023;
    bsum[gid] = l ? (bih2[n] + bhh2[n]) : (bih1[n] + bhh1[n]);
}

// ---------------------------------------------------------------------------
// FULL-RESIDENCY MFMA peephole LSTM — no cross-block communication at all.
// Grid: 16 blocks x 1024 threads (16 waves, 4 waves/SIMD). Block = (l =
// blk>>3, 16-batch chunk). Wave wv owns n-tiles {wv, 16+wv, 32+wv, 48+wv} =
// gates i,f,c,o for units [16wv, 16wv+16): each lane ends the GEMM holding
// ALL 4 gates of its 4 cells -> in-lane activation, c-state in registers.
// ALL 40 B-fragments (full 1024x320 weight matrix) live in this block's
// registers: 160 regs/thread of MFMA B-operands -> AGPRs (unified gfx950
// file; r7's counters proved this placement: VGPR_Count=128 + 160 resident
// weight regs, zero scratch traffic). At 4 waves/SIMD the unified budget is
// 2048/4 = 512 regs/wave; we use ~160 AGPR + ~120 arch VGPR.
// One LDS-only barrier per step. No exchange, no polling, no handshake.
// ---------------------------------------------------------------------------
__global__ __launch_bounds__(1024, 4) void lstm_full(
        const float* __restrict__ x1, const float* __restrict__ x2,
        const float* __restrict__ wci1, const float* __restrict__ wcf1, const float* __restrict__ wco1,
        const float* __restrict__ wci2, const float* __restrict__ wcf2, const float* __restrict__ wco2,
        const f16x8* __restrict__ Bp, const float* __restrict__ bsum,
        float* __restrict__ hseq) {
    const int blk = blockIdx.x;            // 0..15
    const int l   = blk >> 3;
    const int b0  = (blk & 7) * MB;
    const int T    = l ? S2 : S1;
    const int toff = l ? S1 : 0;
    const float* x   = l ? x2 : x1;
    const float* wci = l ? wci2 : wci1;
    const float* wcf = l ? wcf2 : wcf1;
    const float* wco = l ? wco2 : wco1;

    const int tid  = threadIdx.x;
    const int lane = tid & 63;
    const int wv   = tid >> 6;             // wave 0..15 = unit-tile
    const int lr   = lane & 15;            // A batch row / output n-col
    const int lg   = lane >> 4;            // A k-group / output batch-quad
    const int u    = wv * 16 + lr;         // unit 0..255

    __shared__ __align__(16) _Float16 vh[2][MB][VH_STRIDE];  // [x|h] fp16, dbuf

    // zero vh (h of buf0 must be 0 at t=0)
    for (int i = tid; i < 2 * MB * VH_STRIDE / 2; i += 1024) ((int*)vh)[i] = 0;
    __syncthreads();
    // stage x_0 (fp32 -> fp16)
    if (tid < 256) {
        int bb = tid >> 4, k4 = tid & 15;
        float4 v = *(const float4*)(x + ((size_t)(b0 + bb) * T + 0) * I_DIM + 4 * k4);
        f16x4 p = { (_Float16)v.x, (_Float16)v.y, (_Float16)v.z, (_Float16)v.w };
        *(f16x4*)&vh[0][bb][4 * k4] = p;
    }

    // one-time: FULL weight set into registers/AGPRs (40 f16x8 = 160 regs).
    // Per (kk,q): wave reads 64 consecutive f16x8 (1 KB contiguous).
    f16x8 wreg[NKK][4];
    #pragma unroll
    for (int kk = 0; kk < NKK; ++kk)
        #pragma unroll
        for (int q = 0; q < 4; ++q)
            wreg[kk][q] = Bp[(((size_t)l * NKK + kk) * 64 + q * 16 + wv) * 64 + lane];

    float biasv[4];
    #pragma unroll
    for (int q = 0; q < 4; ++q) biasv[q] = bsum[l * 1024 + q * 256 + u];
    const float pi = wci[u], pf = wcf[u], po = wco[u];
    float cst[4] = {0.f, 0.f, 0.f, 0.f};

    int cur = 0;
    __syncthreads();

    for (int t = 0; t < T; ++t) {
        // issue x_{t+1} load early (committed at end of step)
        float4 xn = make_float4(0.f, 0.f, 0.f, 0.f);
        const bool havex = (tid < 256) && (t + 1 < T);
        if (havex)
            xn = *(const float4*)(x + ((size_t)(b0 + (tid >> 4)) * T + (t + 1)) * I_DIM + 4 * (tid & 15));

        f32x4 acc[4];
        #pragma unroll
        for (int q = 0; q < 4; ++q)
            acc[q] = (f32x4){biasv[q], biasv[q], biasv[q], biasv[q]};

#define MK(kk) do {                                                                     \
        f16x8 a_ = *(const f16x8*)&vh[cur][lr][(kk) * 32 + lg * 8];                     \
        acc[0] = __builtin_amdgcn_mfma_f32_16x16x32_f16(a_, wreg[kk][0], acc[0], 0,0,0);\
        acc[1] = __builtin_amdgcn_mfma_f32_16x16x32_f16(a_, wreg[kk][1], acc[1], 0,0,0);\
        acc[2] = __builtin_amdgcn_mfma_f32_16x16x32_f16(a_, wreg[kk][2], acc[2], 0,0,0);\
        acc[3] = __builtin_amdgcn_mfma_f32_16x16x32_f16(a_, wreg[kk][3], acc[3], 0,0,0);\
    } while (0)

        // full K = 320: x part (kk 0,1) + entire h (kk 2..9), all local
        MK(0); MK(1); MK(2); MK(3); MK(4);
        MK(5); MK(6); MK(7); MK(8); MK(9);
#undef MK

        // in-lane activation: 4 cells (batch lg*4+r, unit u)
        #pragma unroll
        for (int r = 0; r < 4; ++r) {
            int b = lg * 4 + r;
            float c  = cst[r];
            float i_ = sigmoidf(acc[0][r] + pi * c);
            float f_ = sigmoidf(acc[1][r] + pf * c);
            float g_ = tanh_fast(acc[2][r]);
            float cy = f_ * c + i_ * g_;
            float o_ = sigmoidf(acc[3][r] + po * cy);
            float hy = o_ * tanh_fast(cy);
            cst[r] = cy;
            vh[cur ^ 1][b][I_DIM + u] = (_Float16)hy;
            hseq[((size_t)(b0 + b) * ST + toff + t) * H_DIM + u] = hy;
        }
        // commit x_{t+1}
        if (havex) {
            f16x4 p = { (_Float16)xn.x, (_Float16)xn.y, (_Float16)xn.z, (_Float16)xn.w };
            *(f16x4*)&vh[cur ^ 1][tid >> 4][4 * (tid & 15)] = p;
        }
        BAR_LDS();   // vh[cur^1] complete; WAR on vh[cur] also covered
        cur ^= 1;
    }
}

// ---------------------------------------------------------------------------
// fc1 split-K partial GEMM (unchanged)
// ---------------------------------------------------------------------------
__global__ __launch_bounds__(256) void fc1_partial(const float* __restrict__ hseq,
                                                   const float* __restrict__ w,
                                                   float* __restrict__ part) {
    const int s  = blockIdx.x;          // 0..NSLICE-1
    const int k0 = s * KC;
    const int kend = (k0 + KC < F1) ? (k0 + KC) : F1;

    __shared__ float As[KCH][129];      // As[k][b]
    __shared__ float Bs[KCH][129];      // Bs[k][j]

    const int tid = threadIdx.x;
    const int tx = tid & 15;            // j block
    const int ty = tid >> 4;            // b block

    float acc[8][8];
    #pragma unroll
    for (int i = 0; i < 8; ++i)
        #pragma unroll
        for (int j = 0; j < 8; ++j) acc[i][j] = 0.f;

    for (int kk = k0; kk < kend; kk += KCH) {
        #pragma unroll
        for (int r = 0; r < 16; ++r) {
            int idx = r * 256 + tid;    // 0..4095
            int row = idx >> 5;
            int k   = idx & 31;
            int gk  = kk + k;
            float av = (gk < F1) ? hseq[(size_t)row * F1 + gk] : 0.f;
            float bv = (gk < F1) ? w[(size_t)row * F1 + gk] : 0.f;
            As[k][row] = av;
            Bs[k][row] = bv;
        }
        __syncthreads();

        #pragma unroll 8
        for (int k = 0; k < KCH; ++k) {
            float av[8], bv[8];
            #pragma unroll
            for (int i = 0; i < 8; ++i) av[i] = As[k][ty * 8 + i];
            #pragma unroll
            for (int j = 0; j < 8; ++j) bv[j] = Bs[k][tx * 8 + j];
            #pragma unroll
            for (int i = 0; i < 8; ++i)
                #pragma unroll
                for (int j = 0; j < 8; ++j)
                    acc[i][j] = fmaf(av[i], bv[j], acc[i][j]);
        }
        __syncthreads();
    }

    float* dst = part + (size_t)s * (BATCH * 128);
    #pragma unroll
    for (int i = 0; i < 8; ++i)
        #pragma unroll
        for (int j = 0; j < 8; ++j)
            dst[(size_t)(ty * 8 + i) * 128 + (tx * 8 + j)] = acc[i][j];
}

__global__ __launch_bounds__(256) void fc1_reduce(const float* __restrict__ part,
                                                  const float* __restrict__ fc1_b,
                                                  float* __restrict__ out1) {
    int flat = blockIdx.x * 256 + threadIdx.x;     // 0..16383
    float sum = 0.f;
    for (int i = 0; i < NSLICE; ++i)
        sum += part[(size_t)i * (BATCH * 128) + flat];
    int j = flat & 127;
    sum += fc1_b[j];
    out1[flat] = fmaxf(sum, 0.f);
}

__global__ __launch_bounds__(128) void fc2_kernel(const float* __restrict__ out1,
                                                  const float* __restrict__ fcw,
                                                  const float* __restrict__ fcb,
                                                  float* __restrict__ out) {
    int b = blockIdx.x;
    __shared__ float ro[128];
    int tid = threadIdx.x;
    ro[tid] = out1[(size_t)b * 128 + tid];
    __syncthreads();
    if (tid < NC) {
        float s = fcb[tid];
        #pragma unroll 8
        for (int j = 0; j < 128; ++j)
            s = fmaf(ro[j], fcw[(size_t)tid * 128 + j], s);
        out[(size_t)b * NC + tid] = s;
    }
}

// ---------------------------------------------------------------------------
extern "C" void kernel_launch(void* const* d_in, const int* in_sizes, int n_in,
                              void* d_out, int out_size, void* d_ws, size_t ws_size,
                              hipStream_t stream) {
    const float* rr_x  = (const float*)d_in[0];
    const float* rr_wv = (const float*)d_in[1];
    const float* w_ih1 = (const float*)d_in[2];
    const float* w_hh1 = (const float*)d_in[3];
    const float* b_ih1 = (const float*)d_in[4];
    const float* b_hh1 = (const float*)d_in[5];
    const float* wci1  = (const float*)d_in[6];
    const float* wcf1  = (const float*)d_in[7];
    const float* wco1  = (const float*)d_in[8];
    const float* w_ih2 = (const float*)d_in[9];
    const float* w_hh2 = (const float*)d_in[10];
    const float* b_ih2 = (const float*)d_in[11];
    const float* b_hh2 = (const float*)d_in[12];
    const float* wci2  = (const float*)d_in[13];
    const float* wcf2  = (const float*)d_in[14];
    const float* wco2  = (const float*)d_in[15];
    const float* fc1_w = (const float*)d_in[16];
    const float* fc1_b = (const float*)d_in[17];
    const float* fc_w  = (const float*)d_in[18];
    const float* fc_b  = (const float*)d_in[19];
    float* out = (float*)d_out;

    char* ws = (char*)d_ws;
    size_t off = 0;
    f16x8* Bp  = (f16x8*)(ws + off);  off += (size_t)2 * NKK * 64 * 64 * sizeof(f16x8); // 1.31 MB
    float* bsum = (float*)(ws + off); off += (size_t)2048 * sizeof(float);
    float* hseq = (float*)(ws + off); off += (size_t)BATCH * F1 * sizeof(float);        // 70.9 MB
    float* part = (float*)(ws + off); off += (size_t)NSLICE * BATCH * 128 * sizeof(float);
    float* out1 = (float*)(ws + off); off += (size_t)BATCH * 128 * sizeof(float);

    prep_pack_b<<<320, 256, 0, stream>>>(w_ih1, w_hh1, w_ih2, w_hh2, Bp);
    prep_bias<<<8, 256, 0, stream>>>(b_ih1, b_hh1, b_ih2, b_hh2, bsum);

    lstm_full<<<16, 1024, 0, stream>>>(rr_x, rr_wv,
                                       wci1, wcf1, wco1, wci2, wcf2, wco2,
                                       Bp, bsum, hseq);

    fc1_partial<<<NSLICE, 256, 0, stream>>>(hseq, fc1_w, part);
    fc1_reduce<<<BATCH * 128 / 256, 256, 0, stream>>>(part, fc1_b, out1);
    fc2_kernel<<<BATCH, 128, 0, stream>>>(out1, fc_w, fc_b, out);
}

// Round 16
// 3897.350 us; speedup vs baseline: 1.6680x; 1.6680x over previous
//
#include <hip/hip_runtime.h>
#include <hip/hip_bf16.h>
#include <hip/hip_fp16.h>
#include <math.h>
#include <stdint.h>

// Problem constants
#define I_DIM 64
#define H_DIM 256
#define NC    10
#define S1    500
#define S2    41
#define BATCH 128
#define ST    (S1 + S2)          // 541
#define F1    (ST * H_DIM)       // 138496
#define NKH   8                  // h-only K-steps of 32 (K=256)
#define MB    16                 // batch rows per chunk
#define VH2   272                // fp16 row stride for h (256 + 16 pad; 2-way max on A-reads)
#define XWROWS (8 * S1 + 8 * S2) // 4328 (c,t) rows in xwp

// fc1 split-K params
#define KC   512
#define KCH  32
#define NSLICE ((F1 + KC - 1) / KC)   // 271

typedef _Float16 f16x8 __attribute__((ext_vector_type(8)));
typedef _Float16 f16x4 __attribute__((ext_vector_type(4)));
typedef _Float16 h2    __attribute__((ext_vector_type(2)));
typedef float    f32x4 __attribute__((ext_vector_type(4)));

#if defined(__has_builtin)
# if __has_builtin(__builtin_amdgcn_fdot2)
#  define FDOT2(a, b, c) __builtin_amdgcn_fdot2((a), (b), (c), false)
# endif
#endif
#ifndef FDOT2
# define FDOT2(a, b, c) fmaf((float)(a)[0], (float)(b)[0], \
                        fmaf((float)(a)[1], (float)(b)[1], (c)))
#endif

__device__ __forceinline__ float dot8(f16x8 a, f16x8 b, float c) {
    union { f16x8 v; h2 p[4]; } ua, ub;
    ua.v = a; ub.v = b;
    c = FDOT2(ua.p[0], ub.p[0], c);
    c = FDOT2(ua.p[1], ub.p[1], c);
    c = FDOT2(ua.p[2], ub.p[2], c);
    c = FDOT2(ua.p[3], ub.p[3], c);
    return c;
}

__device__ __forceinline__ float sigmoidf(float x) {
    return 1.0f / (1.0f + __expf(-x));
}
__device__ __forceinline__ float tanh_fast(float x) {
    float e = __expf(2.0f * x);
    return 1.0f - 2.0f / (e + 1.0f);
}

// LDS-only barrier (r13-proven): cross-thread data at this sync point is LDS,
// so wait lgkmcnt only — skip __syncthreads' vmcnt(0) drain of in-flight
// hseq stores / xw prefetches. SALU-only asm: compiler vmcnt bookkeeping for
// its own loads stays valid.
#define BAR_LDS() do {                                                  \
    __builtin_amdgcn_sched_barrier(0);                                  \
    asm volatile("s_waitcnt lgkmcnt(0)\n\ts_barrier" ::: "memory");     \
    __builtin_amdgcn_sched_barrier(0);                                  \
} while (0)

// chunk c (0..15): l = c>>3, batch base (c&7)*16; xwp row base:
__device__ __forceinline__ size_t xw_cbase(int c) {
    return (c < 8) ? (size_t)c * S1 : (size_t)(8 * S1) + (size_t)(c - 8) * S2;
}

// ---------------------------------------------------------------------------
// Pack w_hh (fp32 [1024][256]) into MFMA B-fragment order, fp16:
//   Bh[ ((l*NKH + kk)*64 + ntg)*64 + lane ]  (one f16x8 per lane)
//   n = ntg*16 + (lane&15);  k_h = kk*32 + (lane>>4)*8 + e   (k_h in [0,256))
// A-frags are read from LDS with the SAME (lane,e)->k map (bijection invariance).
// ---------------------------------------------------------------------------
__global__ __launch_bounds__(256) void prep_pack_bh(
        const float* __restrict__ whh1, const float* __restrict__ whh2,
        f16x8* __restrict__ Bh) {
    int gid = blockIdx.x * 256 + threadIdx.x;      // 0..65535
    int lane = gid & 63;
    int frag = gid >> 6;                           // 0..1023
    int ntg  = frag & 63;
    int kk   = (frag >> 6) & 7;
    int l    = frag >> 9;
    const float* whh = l ? whh2 : whh1;
    int n  = ntg * 16 + (lane & 15);
    int k0 = kk * 32 + (lane >> 4) * 8;
    f16x8 v;
    #pragma unroll
    for (int e = 0; e < 8; ++e)
        v[e] = (_Float16)whh[(size_t)n * H_DIM + k0 + e];
    Bh[gid] = v;
}

// ---------------------------------------------------------------------------
// Precompute xw = x @ w_ih^T + b_ih + b_hh for every (chunk, t), stored fp16
// PRE-SWIZZLED for the recurrent kernel: xwp[(cbase+t)*512 + tid][32] where
// value[ut2*16 + q*4 + r] = gate preact for n = q*256 + (2*wv+ut2)*16 + lr,
// batch b0 + lg*4 + r  (tid -> lane,wv,lr,lg as in lstm_nox).
// Grid: 256 blocks (LSTM1: c=bid>>5, 16 t each) + 24 (LSTM2: 14 t each).
// ---------------------------------------------------------------------------
__global__ __launch_bounds__(512, 2) void prep_xw(
        const float* __restrict__ x1, const float* __restrict__ x2,
        const float* __restrict__ wih1, const float* __restrict__ wih2,
        const float* __restrict__ bih1, const float* __restrict__ bhh1,
        const float* __restrict__ bih2, const float* __restrict__ bhh2,
        _Float16* __restrict__ xwp) {
    const int bid = blockIdx.x;
    int c, t0, tlen;
    if (bid < 256) { c = bid >> 5; t0 = (bid & 31) * 16; tlen = 16; }
    else { int rr = bid - 256; c = 8 + rr / 3; t0 = (rr % 3) * 14; tlen = 14; }
    const int l  = c >> 3;
    const int b0 = (c & 7) * MB;
    const int T  = l ? S2 : S1;
    const float* x   = l ? x2 : x1;
    const float* wih = l ? wih2 : wih1;
    const float* bih = l ? bih2 : bih1;
    const float* bhh = l ? bhh2 : bhh1;
    const size_t cbase = xw_cbase(c);
    const int tend = (t0 + tlen < T) ? (t0 + tlen) : T;

    __shared__ _Float16 wl[1024 * 64];              // w_ih fp16, 128 KB
    __shared__ __align__(16) _Float16 xs[16][64];   // x_t fp16, 2 KB

    const int tid  = threadIdx.x;
    const int lane = tid & 63;
    const int wv   = tid >> 6;
    const int lr   = lane & 15;
    const int lg   = lane >> 4;

    // stage w_ih -> fp16 LDS (each thread 2 rows)
    #pragma unroll
    for (int rr = 0; rr < 2; ++rr) {
        int n = tid * 2 + rr;
        #pragma unroll
        for (int j = 0; j < 16; ++j) {
            float4 v = *(const float4*)(wih + (size_t)n * I_DIM + 4 * j);
            f16x4 p = { (_Float16)v.x, (_Float16)v.y, (_Float16)v.z, (_Float16)v.w };
            *(f16x4*)&wl[n * 64 + 4 * j] = p;
        }
    }
    // per-thread n-rows & biases
    int   nrow[2][4];
    float bias[2][4];
    #pragma unroll
    for (int ut2 = 0; ut2 < 2; ++ut2)
        #pragma unroll
        for (int q = 0; q < 4; ++q) {
            int n = q * 256 + (2 * wv + ut2) * 16 + lr;
            nrow[ut2][q] = n;
            bias[ut2][q] = bih[n] + bhh[n];
        }
    __syncthreads();

    for (int t = t0; t < tend; ++t) {
        if (tid < 256) {
            int bb = tid >> 4, k4 = tid & 15;
            float4 v = *(const float4*)(x + ((size_t)(b0 + bb) * T + t) * I_DIM + 4 * k4);
            f16x4 p = { (_Float16)v.x, (_Float16)v.y, (_Float16)v.z, (_Float16)v.w };
            *(f16x4*)&xs[bb][4 * k4] = p;
        }
        __syncthreads();

        // this thread's 4 batch rows of x into regs (32 f16x8)
        f16x8 xr[4][8];
        #pragma unroll
        for (int r = 0; r < 4; ++r)
            #pragma unroll
            for (int j = 0; j < 8; ++j)
                xr[r][j] = ((const f16x8*)&xs[lg * 4 + r][0])[j];

        f16x8 ov[4];
        #pragma unroll
        for (int ut2 = 0; ut2 < 2; ++ut2)
            #pragma unroll
            for (int q = 0; q < 4; ++q) {
                float a0 = bias[ut2][q], a1 = a0, a2 = a0, a3 = a0;
                const f16x8* wrow = (const f16x8*)&wl[nrow[ut2][q] * 64];
                #pragma unroll
                for (int j = 0; j < 8; ++j) {
                    f16x8 w8 = wrow[j];
                    a0 = dot8(w8, xr[0][j], a0);
                    a1 = dot8(w8, xr[1][j], a1);
                    a2 = dot8(w8, xr[2][j], a2);
                    a3 = dot8(w8, xr[3][j], a3);
                }
                const int base = ut2 * 16 + q * 4;   // compile-time in unrolled loops
                ov[base / 8][base % 8 + 0] = (_Float16)a0;
                ov[base / 8][base % 8 + 1] = (_Float16)a1;
                ov[base / 8][base % 8 + 2] = (_Float16)a2;
                ov[base / 8][base % 8 + 3] = (_Float16)a3;
            }
        f16x8* dst = (f16x8*)xwp + ((cbase + t) * 512 + tid) * 4;
        #pragma unroll
        for (int j = 0; j < 4; ++j) dst[j] = ov[j];
        __syncthreads();   // xs reuse guard
    }
}

// ---------------------------------------------------------------------------
// h-only recurrent MFMA peephole LSTM — NO cross-block communication.
// Grid: 16 blocks x 512 threads (8 waves, launch_bounds(512,2): the r8-proven
// ~288-reg/wave residency envelope). Block = one 16-batch chunk of one LSTM.
// Wave wv owns unit-tiles {2wv, 2wv+1} x 4 gates. Weights (w_hh only, K=256):
// kk 0..5 in registers (48 f16x8 = 192 regs -> VGPR/AGPR unified file),
// kk 6..7 in LDS (131 KB). Gate init = precomputed xw (+biases), loaded as 4
// contiguous dwordx4 per thread, prefetched one step ahead (HBM latency off
// the critical path). One LDS-only barrier per step.
// ---------------------------------------------------------------------------
__global__ __launch_bounds__(512, 2) void lstm_nox(
        const float* __restrict__ wci1, const float* __restrict__ wcf1, const float* __restrict__ wco1,
        const float* __restrict__ wci2, const float* __restrict__ wcf2, const float* __restrict__ wco2,
        const f16x8* __restrict__ Bh, const _Float16* __restrict__ xwp,
        _Float16* __restrict__ hseqh) {
    const int c  = blockIdx.x;             // 0..15
    const int l  = c >> 3;
    const int b0 = (c & 7) * MB;
    const int T    = l ? S2 : S1;
    const int toff = l ? S1 : 0;
    const float* wci = l ? wci2 : wci1;
    const float* wcf = l ? wcf2 : wcf1;
    const float* wco = l ? wco2 : wco1;
    const size_t cbase = xw_cbase(c);

    const int tid  = threadIdx.x;
    const int lane = tid & 63;
    const int wv   = tid >> 6;             // wave 0..7
    const int lr   = lane & 15;
    const int lg   = lane >> 4;
    const int u0   = (2 * wv + 0) * 16 + lr;
    const int u1   = (2 * wv + 1) * 16 + lr;

    __shared__ __align__(16) _Float16 vh[2][MB][VH2];   // h only, dbuf, 17.4 KB
    __shared__ f16x8 Bl[2 * 64 * 64];                   // kk 6,7 B-frags, 131 KB

    // zero vh (h_{-1} = 0)
    for (int i = tid; i < (int)(sizeof(vh) / 4); i += 512) ((int*)vh)[i] = 0;
    // stage Bl (contiguous, coalesced)
    #pragma unroll
    for (int j = 0; j < 16; ++j)
        Bl[tid + j * 512] = Bh[((size_t)l * NKH + 6) * 4096 + tid + j * 512];

    // kk 0..5 weights into registers (unified VGPR/AGPR file)
    f16x8 wreg[6][2][4];
    #pragma unroll
    for (int kk = 0; kk < 6; ++kk)
        #pragma unroll
        for (int ut2 = 0; ut2 < 2; ++ut2)
            #pragma unroll
            for (int q = 0; q < 4; ++q)
                wreg[kk][ut2][q] =
                    Bh[(((size_t)l * NKH + kk) * 64 + q * 16 + 2 * wv + ut2) * 64 + lane];

    const float pi0 = wci[u0], pf0 = wcf[u0], po0 = wco[u0];
    const float pi1 = wci[u1], pf1 = wcf[u1], po1 = wco[u1];
    float cst[2][4] = {{0.f, 0.f, 0.f, 0.f}, {0.f, 0.f, 0.f, 0.f}};

    // first xw row
    f16x8 xq[4];
    {
        const f16x8* p = (const f16x8*)xwp + (cbase * 512 + tid) * 4;
        #pragma unroll
        for (int j = 0; j < 4; ++j) xq[j] = p[j];
    }
    int cur = 0;
    __syncthreads();

    for (int t = 0; t < T; ++t) {
        // acc init from xw (+all biases, folded at prep)
        f32x4 acc[2][4];
        #pragma unroll
        for (int ut2 = 0; ut2 < 2; ++ut2)
            #pragma unroll
            for (int q = 0; q < 4; ++q)
                #pragma unroll
                for (int r = 0; r < 4; ++r)
                    acc[ut2][q][r] = (float)xq[ut2 * 2 + (q >> 1)][(q & 1) * 4 + r];

        // prefetch next step's xw (independent of recurrence)
        f16x8 xn[4];
        const bool havenx = (t + 1 < T);
        if (havenx) {
            const f16x8* p = (const f16x8*)xwp + ((cbase + t + 1) * 512 + tid) * 4;
            #pragma unroll
            for (int j = 0; j < 4; ++j) xn[j] = p[j];
        }
        __builtin_amdgcn_sched_barrier(0);

        // h-part MFMAs: kk 0..5 from regs, kk 6..7 from LDS
        #pragma unroll
        for (int kk = 0; kk < 6; ++kk) {
            f16x8 a = *(const f16x8*)&vh[cur][lr][kk * 32 + lg * 8];
            #pragma unroll
            for (int ut2 = 0; ut2 < 2; ++ut2)
                #pragma unroll
                for (int q = 0; q < 4; ++q)
                    acc[ut2][q] = __builtin_amdgcn_mfma_f32_16x16x32_f16(
                        a, wreg[kk][ut2][q], acc[ut2][q], 0, 0, 0);
        }
        #pragma unroll
        for (int kb = 0; kb < 2; ++kb) {
            f16x8 a = *(const f16x8*)&vh[cur][lr][(6 + kb) * 32 + lg * 8];
            #pragma unroll
            for (int ut2 = 0; ut2 < 2; ++ut2)
                #pragma unroll
                for (int q = 0; q < 4; ++q) {
                    f16x8 b = Bl[kb * 4096 + (q * 16 + 2 * wv + ut2) * 64 + lane];
                    acc[ut2][q] = __builtin_amdgcn_mfma_f32_16x16x32_f16(
                        a, b, acc[ut2][q], 0, 0, 0);
                }
        }

        // in-lane activation: 8 cells (2 units x 4 batch rows)
        #pragma unroll
        for (int ut2 = 0; ut2 < 2; ++ut2) {
            const float pi = ut2 ? pi1 : pi0;
            const float pf = ut2 ? pf1 : pf0;
            const float po = ut2 ? po1 : po0;
            const int   u  = ut2 ? u1 : u0;
            #pragma unroll
            for (int r = 0; r < 4; ++r) {
                int b = lg * 4 + r;
                float cc = cst[ut2][r];
                float i_ = sigmoidf(acc[ut2][0][r] + pi * cc);
                float f_ = sigmoidf(acc[ut2][1][r] + pf * cc);
                float g_ = tanh_fast(acc[ut2][2][r]);
                float cy = f_ * cc + i_ * g_;
                float o_ = sigmoidf(acc[ut2][3][r] + po * cy);
                _Float16 h16 = (_Float16)(o_ * tanh_fast(cy));
                cst[ut2][r] = cy;
                vh[cur ^ 1][b][u] = h16;
                hseqh[((size_t)(b0 + b) * ST + toff + t) * H_DIM + u] = h16;
            }
        }
        // rotate xw prefetch
        if (havenx) {
            #pragma unroll
            for (int j = 0; j < 4; ++j) xq[j] = xn[j];
        }
        BAR_LDS();   // vh[cur^1] complete; WAR on vh[cur] covered
        cur ^= 1;
    }
}

// ---------------------------------------------------------------------------
// fc1 split-K partial GEMM — hseq now fp16
// ---------------------------------------------------------------------------
__global__ __launch_bounds__(256) void fc1_partial(const _Float16* __restrict__ hseqh,
                                                   const float* __restrict__ w,
                                                   float* __restrict__ part) {
    const int s  = blockIdx.x;          // 0..NSLICE-1
    const int k0 = s * KC;
    const int kend = (k0 + KC < F1) ? (k0 + KC) : F1;

    __shared__ float As[KCH][129];      // As[k][b]
    __shared__ float Bs[KCH][129];      // Bs[k][j]

    const int tid = threadIdx.x;
    const int tx = tid & 15;            // j block
    const int ty = tid >> 4;            // b block

    float acc[8][8];
    #pragma unroll
    for (int i = 0; i < 8; ++i)
        #pragma unroll
        for (int j = 0; j < 8; ++j) acc[i][j] = 0.f;

    for (int kk = k0; kk < kend; kk += KCH) {
        #pragma unroll
        for (int r = 0; r < 16; ++r) {
            int idx = r * 256 + tid;    // 0..4095
            int row = idx >> 5;
            int k   = idx & 31;
            int gk  = kk + k;
            float av = (gk < F1) ? (float)hseqh[(size_t)row * F1 + gk] : 0.f;
            float bv = (gk < F1) ? w[(size_t)row * F1 + gk] : 0.f;
            As[k][row] = av;
            Bs[k][row] = bv;
        }
        __syncthreads();

        #pragma unroll 8
        for (int k = 0; k < KCH; ++k) {
            float av[8], bv[8];
            #pragma unroll
            for (int i = 0; i < 8; ++i) av[i] = As[k][ty * 8 + i];
            #pragma unroll
            for (int j = 0; j < 8; ++j) bv[j] = Bs[k][tx * 8 + j];
            #pragma unroll
            for (int i = 0; i < 8; ++i)
                #pragma unroll
                for (int j = 0; j < 8; ++j)
                    acc[i][j] = fmaf(av[i], bv[j], acc[i][j]);
        }
        __syncthreads();
    }

    float* dst = part + (size_t)s * (BATCH * 128);
    #pragma unroll
    for (int i = 0; i < 8; ++i)
        #pragma unroll
        for (int j = 0; j < 8; ++j)
            dst[(size_t)(ty * 8 + i) * 128 + (tx * 8 + j)] = acc[i][j];
}

__global__ __launch_bounds__(256) void fc1_reduce(const float* __restrict__ part,
                                                  const float* __restrict__ fc1_b,
                                                  float* __restrict__ out1) {
    int flat = blockIdx.x * 256 + threadIdx.x;     // 0..16383
    float sum = 0.f;
    for (int i = 0; i < NSLICE; ++i)
        sum += part[(size_t)i * (BATCH * 128) + flat];
    int j = flat & 127;
    sum += fc1_b[j];
    out1[flat] = fmaxf(sum, 0.f);
}

__global__ __launch_bounds__(128) void fc2_kernel(const float* __restrict__ out1,
                                                  const float* __restrict__ fcw,
                                                  const float* __restrict__ fcb,
                                                  float* __restrict__ out) {
    int b = blockIdx.x;
    __shared__ float ro[128];
    int tid = threadIdx.x;
    ro[tid] = out1[(size_t)b * 128 + tid];
    __syncthreads();
    if (tid < NC) {
        float s = fcb[tid];
        #pragma unroll 8
        for (int j = 0; j < 128; ++j)
            s = fmaf(ro[j], fcw[(size_t)tid * 128 + j], s);
        out[(size_t)b * NC + tid] = s;
    }
}

// ---------------------------------------------------------------------------
extern "C" void kernel_launch(void* const* d_in, const int* in_sizes, int n_in,
                              void* d_out, int out_size, void* d_ws, size_t ws_size,
                              hipStream_t stream) {
    const float* rr_x  = (const float*)d_in[0];
    const float* rr_wv = (const float*)d_in[1];
    const float* w_ih1 = (const float*)d_in[2];
    const float* w_hh1 = (const float*)d_in[3];
    const float* b_ih1 = (const float*)d_in[4];
    const float* b_hh1 = (const float*)d_in[5];
    const float* wci1  = (const float*)d_in[6];
    const float* wcf1  = (const float*)d_in[7];
    const float* wco1  = (const float*)d_in[8];
    const float* w_ih2 = (const float*)d_in[9];
    const float* w_hh2 = (const float*)d_in[10];
    const float* b_ih2 = (const float*)d_in[11];
    const float* b_hh2 = (const float*)d_in[12];
    const float* wci2  = (const float*)d_in[13];
    const float* wcf2  = (const float*)d_in[14];
    const float* wco2  = (const float*)d_in[15];
    const float* fc1_w = (const float*)d_in[16];
    const float* fc1_b = (const float*)d_in[17];
    const float* fc_w  = (const float*)d_in[18];
    const float* fc_b  = (const float*)d_in[19];
    float* out = (float*)d_out;

    // workspace: Bh | hseqh | out1 | xwp ; part ALIASES xwp (dead by fc1 time)
    char* ws = (char*)d_ws;
    size_t off = 0;
    f16x8*    Bh    = (f16x8*)(ws + off);    off += (size_t)2 * NKH * 64 * 64 * sizeof(f16x8); // 1.05 MB
    _Float16* hseqh = (_Float16*)(ws + off); off += (size_t)BATCH * F1 * sizeof(_Float16);     // 35.5 MB
    float*    out1  = (float*)(ws + off);    off += (size_t)BATCH * 128 * sizeof(float);
    _Float16* xwp   = (_Float16*)(ws + off); off += (size_t)XWROWS * 512 * 32 * sizeof(_Float16); // 141.8 MB
    float*    part  = (float*)xwp;           // 17.8 MB <= xwp size; sequential reuse

    prep_pack_bh<<<256, 256, 0, stream>>>(w_hh1, w_hh2, Bh);
    prep_xw<<<280, 512, 0, stream>>>(rr_x, rr_wv, w_ih1, w_ih2,
                                     b_ih1, b_hh1, b_ih2, b_hh2, xwp);

    lstm_nox<<<16, 512, 0, stream>>>(wci1, wcf1, wco1, wci2, wcf2, wco2,
                                     Bh, xwp, hseqh);

    fc1_partial<<<NSLICE, 256, 0, stream>>>(hseqh, fc1_w, part);
    fc1_reduce<<<BATCH * 128 / 256, 256, 0, stream>>>(part, fc1_b, out1);
    fc2_kernel<<<BATCH, 128, 0, stream>>>(out1, fc_w, fc_b, out);
}